// Round 1
// baseline (146.928 us; speedup 1.0000x reference)
//
#include <hip/hip_runtime.h>
#include <math.h>

#define HF 37
#define WF 50
#define CC 512
#define POOLD 7
#define SAMPD 14

// One block per (roi, pooled_y, pooled_x) bin. 128 threads * float4 = 512 channels.
__global__ __launch_bounds__(128) void roipool_kernel(
    const float* __restrict__ feat,   // [HF, WF, CC]
    const float* __restrict__ rois,   // [N, 4] (x1,y1,x2,y2) image coords
    const int*   __restrict__ im_size,// [2] (h, w)
    float*       __restrict__ out,    // [N, 7, 7, CC]
    int N)
{
    int bid = blockIdx.x;
    int n   = bid / (POOLD * POOLD);
    if (n >= N) return;
    int rem = bid - n * (POOLD * POOLD);
    int py  = rem / POOLD;
    int px  = rem - py * POOLD;

    float h = (float)im_size[0];
    float w = (float)im_size[1];
    float bx1 = rois[4 * n + 0];
    float by1 = rois[4 * n + 1];
    float bx2 = rois[4 * n + 2];
    float by2 = rois[4 * n + 3];
    float ny1 = by1 / h, nx1 = bx1 / w;
    float ny2 = by2 / h, nx2 = bx2 / w;

    const float inv = 1.0f / (float)(SAMPD - 1);  // t step = s/13

    int c = (int)threadIdx.x * 4;

    float4 acc = make_float4(-INFINITY, -INFINITY, -INFINITY, -INFINITY);

    #pragma unroll
    for (int dy = 0; dy < 2; ++dy) {
        int sy = 2 * py + dy;
        float ty = (float)sy * inv;
        float ys = (ny1 + (ny2 - ny1) * ty) * (float)(HF - 1);
        ys = fminf(fmaxf(ys, 0.0f), (float)(HF - 1));
        float y0f = floorf(ys);
        int iy0 = (int)y0f;
        int iy1 = min(iy0 + 1, HF - 1);
        float wy = ys - y0f;

        #pragma unroll
        for (int dx = 0; dx < 2; ++dx) {
            int sx = 2 * px + dx;
            float tx = (float)sx * inv;
            float xs = (nx1 + (nx2 - nx1) * tx) * (float)(WF - 1);
            xs = fminf(fmaxf(xs, 0.0f), (float)(WF - 1));
            float x0f = floorf(xs);
            int ix0 = (int)x0f;
            int ix1 = min(ix0 + 1, WF - 1);
            float wx = xs - x0f;

            const float4* p00 = (const float4*)(feat + ((size_t)(iy0 * WF + ix0) * CC + c));
            const float4* p01 = (const float4*)(feat + ((size_t)(iy0 * WF + ix1) * CC + c));
            const float4* p10 = (const float4*)(feat + ((size_t)(iy1 * WF + ix0) * CC + c));
            const float4* p11 = (const float4*)(feat + ((size_t)(iy1 * WF + ix1) * CC + c));
            float4 v00 = *p00;
            float4 v01 = *p01;
            float4 v10 = *p10;
            float4 v11 = *p11;

            float w00 = (1.0f - wy) * (1.0f - wx);
            float w01 = (1.0f - wy) * wx;
            float w10 = wy * (1.0f - wx);
            float w11 = wy * wx;

            float4 val;
            val.x = v00.x * w00 + v01.x * w01 + v10.x * w10 + v11.x * w11;
            val.y = v00.y * w00 + v01.y * w01 + v10.y * w10 + v11.y * w11;
            val.z = v00.z * w00 + v01.z * w01 + v10.z * w10 + v11.z * w11;
            val.w = v00.w * w00 + v01.w * w01 + v10.w * w10 + v11.w * w11;

            acc.x = fmaxf(acc.x, val.x);
            acc.y = fmaxf(acc.y, val.y);
            acc.z = fmaxf(acc.z, val.z);
            acc.w = fmaxf(acc.w, val.w);
        }
    }

    float4* dst = (float4*)(out + ((size_t)((n * POOLD + py) * POOLD + px) * CC + c));
    *dst = acc;
}

extern "C" void kernel_launch(void* const* d_in, const int* in_sizes, int n_in,
                              void* d_out, int out_size, void* d_ws, size_t ws_size,
                              hipStream_t stream) {
    const float* feat    = (const float*)d_in[0];   // [1,37,50,512]
    const float* rois    = (const float*)d_in[1];   // [N,4]
    const int*   im_size = (const int*)d_in[2];     // [2]
    float* out = (float*)d_out;

    int N = in_sizes[1] / 4;
    int nblocks = N * POOLD * POOLD;
    roipool_kernel<<<nblocks, 128, 0, stream>>>(feat, rois, im_size, out, N);
}